// Round 1
// baseline (29924.557 us; speedup 1.0000x reference)
//
#include <hip/hip_runtime.h>
#include <cstdint>
#include <cstddef>

// Problem constants (fixed by the reference)
#define DD 1024
#define TT 2048
#define NL 4
// Persistent-kernel config
#define NBLK 128         // blocks; each owns 32 of 4096 z-columns
#define NTHR 1024        // 16 waves; 2 cols per wave
#define NSUB 8           // sub-flags to spread atomic contention
#define SUBTARGET (NBLK / NSUB)   // 16 blocks per sub-flag

__device__ __forceinline__ float fast_tanh(float x) {
  // robust: no NaN for large |x|
  float e = __expf(2.f * x);
  return 1.f - 2.f / (e + 1.f);
}

__global__ __launch_bounds__(1024) void prep_kernel(
    const float* __restrict__ sp, const float* __restrict__ rn_p,
    const float* __restrict__ w, const float* __restrict__ b,
    float* __restrict__ X0) {
  int i = blockIdx.x * blockDim.x + threadIdx.x;   // over T*D
  float rn = rn_p[0];
  int c = i & (DD - 1);
  X0[i] = sp[i] + rn * w[c] + b[c];
}

// One layer of the CfC recurrence. Persistent: NBLK blocks, all co-resident.
// Block bid computes h outputs [bid*8, bid*8+8) each step.
// Cross-block sync: per-timestep sub-flag counters with agent-scope atomics;
// h exchanged through Hout with agent-scope (sc0 sc1) loads/stores so per-XCD
// L2 non-coherence cannot serve stale data.
__global__ __launch_bounds__(NTHR) void recur_kernel(
    const float* __restrict__ Xin, float* __restrict__ Hout,
    const float* __restrict__ Wf1, const float* __restrict__ Wf2,
    const float* __restrict__ Wta, const float* __restrict__ Wtb,
    const float* __restrict__ bf1, const float* __restrict__ bf2,
    const float* __restrict__ bta, const float* __restrict__ btb,
    const float* __restrict__ dt_p, int layer,
    int* __restrict__ flags,       // [NSUB][TT], pre-zeroed
    float* __restrict__ out_last)  // d_out for last layer, else nullptr
{
  __shared__ float xh[2 * DD];   // [x_t (1024) ; h_{t-1} (1024)]
  __shared__ float zbuf[32];     // this block's 32 z-columns

  const int tid = threadIdx.x;
  const int w   = tid >> 6;      // wave 0..15
  const int ln  = tid & 63;      // lane
  const int bid = blockIdx.x;

  // Column assignment: col_local = 2w, 2w+1 in [0,32); matrix B = col_local/8.
  const int B   = w >> 2;
  const int il0 = (2 * w) & 7;
  const int col0 = bid * 8 + il0;          // col1 = col0 + 1 (same matrix)
  const float* Wsel = (B == 0) ? Wf1 : (B == 1) ? Wf2 : (B == 2) ? Wta : Wtb;
  const float* Wb = Wsel + (size_t)layer * 2 * DD * DD;

  // Load stationary weights into registers: 32 rows per lane for each of 2 cols.
  // Row mapping: row = seg*128 + 2*ln + j  (matches LDS float2 read pattern,
  // conflict-free: lanes hit consecutive bank pairs).
  float w0[32], w1[32];
#pragma unroll
  for (int seg = 0; seg < 16; ++seg) {
#pragma unroll
    for (int j = 0; j < 2; ++j) {
      int row = seg * 128 + 2 * ln + j;
      float2 ww = *(const float2*)&Wb[(size_t)row * DD + col0];  // col0 even -> 8B aligned
      w0[seg * 2 + j] = ww.x;
      w1[seg * 2 + j] = ww.y;
    }
  }

  // Combine-thread constants (threads 0..7 produce the 8 h outputs)
  float bias1 = 0.f, bias2 = 0.f, biasa = 0.f, biasb = 0.f;
  const float dtv = dt_p[0];
  if (tid < 8) {
    int col = bid * 8 + tid;
    bias1 = bf1[layer * DD + col];
    bias2 = bf2[layer * DD + col];
    biasa = bta[layer * DD + col];
    biasb = btb[layer * DD + col];
  }

  for (int t = 0; t < TT; ++t) {
    // x_t is known ahead of time: issue its load before waiting on h_{t-1}.
    float xreg = Xin[(size_t)t * DD + tid];

    if (t > 0 && w == 0) {
      // Wave 0 spins: lanes 0..7 each poll one sub-flag of step t-1.
      long guard = 0;
      while (true) {
        int v = SUBTARGET;
        if (ln < NSUB)
          v = __hip_atomic_load(&flags[ln * TT + (t - 1)],
                                __ATOMIC_RELAXED, __HIP_MEMORY_SCOPE_AGENT);
        if (__all((ln >= NSUB) || (v >= SUBTARGET))) break;
        if (++guard > 100000000L) break;  // hang bail-out (should never trip)
      }
    }
    __syncthreads();   // publish spin result; protect LDS reuse

    xh[tid] = xreg;
    float hreg = 0.f;
    if (t > 0)
      hreg = __hip_atomic_load(&Hout[(size_t)(t - 1) * DD + tid],
                               __ATOMIC_RELAXED, __HIP_MEMORY_SCOPE_AGENT);
    xh[DD + tid] = hreg;
    __syncthreads();

    // Dot products: 2 columns per wave over all 2048 rows.
    float acc0 = 0.f, acc1 = 0.f;
#pragma unroll
    for (int seg = 0; seg < 16; ++seg) {
      float2 v = *(const float2*)&xh[seg * 128 + 2 * ln];
      acc0 += v.x * w0[2 * seg] + v.y * w0[2 * seg + 1];
      acc1 += v.x * w1[2 * seg] + v.y * w1[2 * seg + 1];
    }
#pragma unroll
    for (int off = 32; off > 0; off >>= 1) {
      acc0 += __shfl_xor(acc0, off, 64);
      acc1 += __shfl_xor(acc1, off, 64);
    }
    if (ln == 0) { zbuf[2 * w] = acc0; zbuf[2 * w + 1] = acc1; }
    __syncthreads();

    if (tid < 8) {
      float z1 = zbuf[tid]      + bias1;
      float z2 = zbuf[8 + tid]  + bias2;
      float za = zbuf[16 + tid] + biasa;
      float zb = zbuf[24 + tid] + biasb;
      float f1 = fast_tanh(z1);
      float f2 = fast_tanh(z2);
      // gate = sigmoid(-za*dt + zb) = 1/(1+exp(za*dt - zb))
      float g = 1.f / (1.f + __expf(za * dtv - zb));
      float h = g * f1 + (1.f - g) * f2;
      int col = bid * 8 + tid;
      __hip_atomic_store(&Hout[(size_t)t * DD + col], h,
                         __ATOMIC_RELAXED, __HIP_MEMORY_SCOPE_AGENT);
      if (out_last && t == TT - 1) out_last[col] = h;
      if (tid == 0) {
        // Release: orders this wave's sc1 h-stores (lanes 0..7) before the add.
        __hip_atomic_fetch_add(&flags[(bid & (NSUB - 1)) * TT + t], 1,
                               __ATOMIC_RELEASE, __HIP_MEMORY_SCOPE_AGENT);
      }
    }
  }
}

extern "C" void kernel_launch(void* const* d_in, const int* in_sizes, int n_in,
                              void* d_out, int out_size, void* d_ws, size_t ws_size,
                              hipStream_t stream) {
  const float* sp  = (const float*)d_in[0];
  const float* rn  = (const float*)d_in[1];
  const float* dt  = (const float*)d_in[2];
  const float* rw  = (const float*)d_in[3];
  const float* rb  = (const float*)d_in[4];
  const float* Wf1 = (const float*)d_in[5];
  const float* bf1 = (const float*)d_in[6];
  const float* Wf2 = (const float*)d_in[7];
  const float* bf2 = (const float*)d_in[8];
  const float* Wta = (const float*)d_in[9];
  const float* bta = (const float*)d_in[10];
  const float* Wtb = (const float*)d_in[11];
  const float* btb = (const float*)d_in[12];

  float* ws = (float*)d_ws;
  float* A  = ws;                        // T*D
  float* Bb = ws + (size_t)TT * DD;      // T*D
  int* flags = (int*)(ws + (size_t)2 * TT * DD);  // NL*NSUB*TT ints
  float* out = (float*)d_out;

  // ws is re-poisoned 0xAA before every timed launch: zero the flags each call.
  hipMemsetAsync(flags, 0, sizeof(int) * NL * NSUB * TT, stream);

  // X0 = spatial + re_norm*re_proj_w + re_proj_b
  prep_kernel<<<(TT * DD) / 1024, 1024, 0, stream>>>(sp, rn, rw, rb, A);

  // 4 layers, ping-ponging A/B. Kernel boundaries give agent-scope cache
  // release/acquire so the next layer's plain x reads see the sc1 h writes.
  recur_kernel<<<NBLK, NTHR, 0, stream>>>(A, Bb, Wf1, Wf2, Wta, Wtb,
      bf1, bf2, bta, btb, dt, 0, flags + 0 * NSUB * TT, nullptr);
  recur_kernel<<<NBLK, NTHR, 0, stream>>>(Bb, A, Wf1, Wf2, Wta, Wtb,
      bf1, bf2, bta, btb, dt, 1, flags + 1 * NSUB * TT, nullptr);
  recur_kernel<<<NBLK, NTHR, 0, stream>>>(A, Bb, Wf1, Wf2, Wta, Wtb,
      bf1, bf2, bta, btb, dt, 2, flags + 2 * NSUB * TT, nullptr);
  recur_kernel<<<NBLK, NTHR, 0, stream>>>(Bb, A, Wf1, Wf2, Wta, Wtb,
      bf1, bf2, bta, btb, dt, 3, flags + 3 * NSUB * TT, out);
}